// Round 3
// baseline (7873.470 us; speedup 1.0000x reference)
//
#include <hip/hip_runtime.h>
#include <stdint.h>

typedef unsigned short ushort_t;
typedef unsigned int uint32;

// ---------- sizes (fixed by the problem) ----------
#define NT 20000
#define NC 200000
#define NF 40000
#define E_HC 200000
#define E_BT 200000
#define E_IS 80000
#define E_PT 80000
#define FDIM 256   // H*D
#define NHEAD 4
#define DHEAD 64

// ---------- helpers ----------
__device__ __forceinline__ float blo(uint32 u) { return __uint_as_float(u << 16); }
__device__ __forceinline__ float bhi(uint32 u) { return __uint_as_float(u & 0xFFFF0000u); }
__device__ __forceinline__ ushort_t f2b_raw(float f) {
    unsigned u = __float_as_uint(f);
    unsigned r = u + 0x7fffu + ((u >> 16) & 1u);   // RNE
    return (ushort_t)(r >> 16);
}
// monotone float<->uint encoding for atomicMax on signed floats
__device__ __forceinline__ unsigned fenc(float f) {
    unsigned u = __float_as_uint(f);
    return (u & 0x80000000u) ? ~u : (u | 0x80000000u);
}
__device__ __forceinline__ float fdec(unsigned u) {
    u = (u & 0x80000000u) ? (u & 0x7fffffffu) : ~u;
    return __uint_as_float(u);
}
__device__ __forceinline__ float finclamp(float v) {
    // NaN -> -1e30 (finite); +-inf -> +-1e30. No-op for sane values.
    return fminf(fmaxf(v, -1e30f), 1e30f);
}

// ---------- GEMM: C[M,N] = act(A[M,K] @ W[K,N] + bias[N]) ----------
// AT: 0 = A is fp32, 1 = A is bf16(raw ushort). W, bias always fp32.
// CT: 0 = C is fp32, 1 = C is bf16(raw ushort). fp32 accumulate.
// BM=128, BN=64, BK=16; 256 threads; each thread computes 8x4.
// act: 0 = none, 1 = leaky_relu(0.01)
#define BM 128
#define BN 64
#define BK 16
template<int AT, int CT>
__global__ __launch_bounds__(256) void gemm_k(
    const void* __restrict__ Av, const float* __restrict__ W,
    const float* __restrict__ bias, void* __restrict__ Cv,
    int M, int N, int K, int act)
{
    __shared__ float As[BK][BM + 1];
    __shared__ float Ws[BK][BN + 1];
    const int t  = threadIdx.x;
    const int m0 = blockIdx.x * BM;
    const int n0 = blockIdx.y * BN;
    const int tx = t & 15, ty = t >> 4;
    const int am = t >> 1;           // 0..127
    const int ak = (t & 1) * 8;      // 0 or 8
    const int wk = t >> 4;           // 0..15
    const int wn = (t & 15) * 4;     // 0..60

    float acc[8][4];
#pragma unroll
    for (int i = 0; i < 8; i++)
#pragma unroll
        for (int j = 0; j < 4; j++) acc[i][j] = 0.f;

    for (int k0 = 0; k0 < K; k0 += BK) {
        // stage A tile [BM x BK] -> As[k][m]; 8 consecutive elems per thread.
        // elem offset arow*K + k0 + ak is a multiple of 8 (K,k0 mult 16, ak in {0,8}).
        {
            float vals[8];
            int arow = m0 + am;
            if (arow < M) {
                if (AT == 0) {
                    const float* A = (const float*)Av;
                    const float4* p = reinterpret_cast<const float4*>(
                        A + (size_t)arow * K + k0 + ak);   // 32B aligned
                    float4 q0 = p[0], q1 = p[1];
                    vals[0] = q0.x; vals[1] = q0.y; vals[2] = q0.z; vals[3] = q0.w;
                    vals[4] = q1.x; vals[5] = q1.y; vals[6] = q1.z; vals[7] = q1.w;
                } else {
                    const ushort_t* A = (const ushort_t*)Av;
                    uint4 q = *reinterpret_cast<const uint4*>(
                        A + (size_t)arow * K + k0 + ak);   // 16B aligned
                    vals[0] = blo(q.x); vals[1] = bhi(q.x);
                    vals[2] = blo(q.y); vals[3] = bhi(q.y);
                    vals[4] = blo(q.z); vals[5] = bhi(q.z);
                    vals[6] = blo(q.w); vals[7] = bhi(q.w);
                }
            } else {
#pragma unroll
                for (int i = 0; i < 8; i++) vals[i] = 0.f;
            }
#pragma unroll
            for (int i = 0; i < 8; i++) As[ak + i][am] = vals[i];
        }
        // stage W tile [BK x BN] -> Ws[k][n]  (fp32, 16B-aligned float4)
        {
            float4 q = *reinterpret_cast<const float4*>(
                W + (size_t)(k0 + wk) * N + n0 + wn);
            Ws[wk][wn + 0] = q.x;
            Ws[wk][wn + 1] = q.y;
            Ws[wk][wn + 2] = q.z;
            Ws[wk][wn + 3] = q.w;
        }
        __syncthreads();
#pragma unroll
        for (int kk = 0; kk < BK; ++kk) {
            float a[8], w[4];
#pragma unroll
            for (int i = 0; i < 8; i++) a[i] = As[kk][ty * 8 + i];
#pragma unroll
            for (int j = 0; j < 4; j++) w[j] = Ws[kk][tx * 4 + j];
#pragma unroll
            for (int i = 0; i < 8; i++)
#pragma unroll
                for (int j = 0; j < 4; j++) acc[i][j] += a[i] * w[j];
        }
        __syncthreads();
    }

    float bv[4] = {0.f, 0.f, 0.f, 0.f};
    if (bias) {
#pragma unroll
        for (int j = 0; j < 4; j++) bv[j] = bias[n0 + tx * 4 + j];
    }
#pragma unroll
    for (int i = 0; i < 8; i++) {
        int r = m0 + ty * 8 + i;
        if (r >= M) continue;
        size_t base = (size_t)r * N + n0 + tx * 4;
        float v[4];
#pragma unroll
        for (int j = 0; j < 4; j++) {
            float x = acc[i][j] + bv[j];
            if (act == 1) x = (x > 0.f) ? x : 0.01f * x;
            v[j] = finclamp(x);
        }
        if (CT == 0) {
            float* C = (float*)Cv;
            *reinterpret_cast<float4*>(C + base) = make_float4(v[0], v[1], v[2], v[3]);
        } else {
            ushort_t* C = (ushort_t*)Cv;
            uint32 lo = ((uint32)f2b_raw(v[1]) << 16) | (uint32)f2b_raw(v[0]);
            uint32 hi = ((uint32)f2b_raw(v[3]) << 16) | (uint32)f2b_raw(v[2]);
            *reinterpret_cast<uint2*>(C + base) = make_uint2(lo, hi);
        }
    }
}

// ---------- init kernels ----------
__global__ void fill_bias_k(float* __restrict__ o, const float* __restrict__ b1,
                            const float* __restrict__ b2, int n) {
    int i = blockIdx.x * 256 + threadIdx.x;
    if (i >= n) return;
    int f = i & 255;
    float v = b1[f];
    if (b2) v += b2[f];
    o[i] = v;
}

__global__ void init_md_k(unsigned* __restrict__ m, float* __restrict__ den, int n) {
    int i = blockIdx.x * 256 + threadIdx.x;
    if (i < n) { m[i] = fenc(-1e30f); den[i] = 0.f; }
}

// ---------- edge pass A: logits + segment max ----------
// one wave (64 lanes) per edge; lane handles features lane*4 .. lane*4+3
__global__ __launch_bounds__(256) void edge_logits_k(
    const ushort_t* __restrict__ xl, const ushort_t* __restrict__ xr,
    const float* __restrict__ att,
    const int* __restrict__ src, const int* __restrict__ dst,
    float* __restrict__ logit, unsigned* __restrict__ mbuf, int E)
{
    int e = blockIdx.x * 4 + (threadIdx.x >> 6);
    if (e >= E) return;
    int lane = threadIdx.x & 63;
    int f = lane * 4;
    float4 qa = *reinterpret_cast<const float4*>(att + f);   // fp32 att, 16B aligned
    int s = src[e], d = dst[e];
    uint2 ql = *reinterpret_cast<const uint2*>(xl + (size_t)s * FDIM + f);
    uint2 qr = *reinterpret_cast<const uint2*>(xr + (size_t)d * FDIM + f);
    float v0 = blo(ql.x) + blo(qr.x);
    float v1 = bhi(ql.x) + bhi(qr.x);
    float v2 = blo(ql.y) + blo(qr.y);
    float v3 = bhi(ql.y) + bhi(qr.y);
    v0 = (v0 > 0.f) ? v0 : 0.2f * v0;
    v1 = (v1 > 0.f) ? v1 : 0.2f * v1;
    v2 = (v2 > 0.f) ? v2 : 0.2f * v2;
    v3 = (v3 > 0.f) ? v3 : 0.2f * v3;
    float sum = qa.x * v0 + qa.y * v1 + qa.z * v2 + qa.w * v3;
    // reduce within each 16-lane head group
    sum += __shfl_xor(sum, 1);
    sum += __shfl_xor(sum, 2);
    sum += __shfl_xor(sum, 4);
    sum += __shfl_xor(sum, 8);
    if ((lane & 15) == 0) {
        int h = lane >> 4;
        logit[(size_t)e * NHEAD + h] = sum;
        atomicMax(&mbuf[(size_t)d * NHEAD + h], fenc(sum));
    }
}

// ---------- edge pass B: z = exp(min(logit - m[dst],0)); den += z ----------
__global__ void edge_z_k(const int* __restrict__ dst, float* __restrict__ logit,
                         const unsigned* __restrict__ mbuf, float* __restrict__ den, int E)
{
    int i = blockIdx.x * 256 + threadIdx.x;
    if (i >= E * NHEAD) return;
    int e = i >> 2, h = i & 3;
    int d = dst[e];
    float mv = fdec(mbuf[(size_t)d * NHEAD + h]);
    // clamp is a no-op when m is the true segment max (max edge still gets z=1);
    // converts any failure into bounded error instead of inf/NaN.
    float z = expf(fminf(logit[i] - mv, 0.f));
    logit[i] = z;
    atomicAdd(&den[(size_t)d * NHEAD + h], z);
}

// ---------- edge pass C: out[dst] += alpha * xl[src] ----------
__global__ __launch_bounds__(256) void edge_scatter_k(
    const ushort_t* __restrict__ xl,
    const int* __restrict__ src, const int* __restrict__ dst,
    const float* __restrict__ z, const float* __restrict__ den,
    float* __restrict__ out, int E)
{
    int e = blockIdx.x * 4 + (threadIdx.x >> 6);
    if (e >= E) return;
    int lane = threadIdx.x & 63;
    int f = lane * 4;
    int h = lane >> 4;
    int s = src[e], d = dst[e];
    float alpha = z[(size_t)e * NHEAD + h] / fmaxf(den[(size_t)d * NHEAD + h], 1e-20f);
    // alpha in [0,1] by construction; clamp no-op when correct, kills NaN/inf otherwise.
    alpha = fminf(fmaxf(alpha, 0.f), 1.f);
    uint2 ql = *reinterpret_cast<const uint2*>(xl + (size_t)s * FDIM + f);
    float* op = out + (size_t)d * FDIM + f;
    atomicAdd(op + 0, alpha * blo(ql.x));
    atomicAdd(op + 1, alpha * bhi(ql.x));
    atomicAdd(op + 2, alpha * blo(ql.y));
    atomicAdd(op + 3, alpha * bhi(ql.y));
}

// ---------- combine: x = elu(scale * o) -> bf16 ----------
__global__ void combine_elu_k(const float* __restrict__ o, ushort_t* __restrict__ x,
                              float scale, int n)
{
    int i = blockIdx.x * 256 + threadIdx.x;
    if (i >= n) return;
    float v = scale * o[i];
    v = (v > 0.f) ? v : (expf(v) - 1.f);
    x[i] = f2b_raw(finclamp(v));
}

// ---------- host launch ----------
extern "C" void kernel_launch(void* const* d_in, const int* in_sizes, int n_in,
                              void* d_out, int out_size, void* d_ws, size_t ws_size,
                              hipStream_t stream) {
    (void)in_sizes; (void)n_in; (void)out_size;
    // Inputs are float32 per the reference (setup_inputs uses jnp.float32).
    const float* x_table = (const float*)d_in[0];
    const float* x_column = (const float*)d_in[1];
    const float* x_fk = (const float*)d_in[2];
    const float* lin_w = (const float*)d_in[3];   // [3,256,64]
    const float* lin_b = (const float*)d_in[4];   // [3,64]
    const float* out_w = (const float*)d_in[5];   // [3,256,256]
    const float* out_b = (const float*)d_in[6];   // [3,256]
    const float* Wl0 = (const float*)d_in[7];     // [4,64,256]
    const float* Wr0 = (const float*)d_in[8];
    const float* att0 = (const float*)d_in[9];    // [4,4,64]
    const float* b0 = (const float*)d_in[10];     // [4,256]
    const float* Wl1 = (const float*)d_in[11];    // [4,256,256]
    const float* Wr1 = (const float*)d_in[12];
    const float* att1 = (const float*)d_in[13];
    const float* b1 = (const float*)d_in[14];
    const int* src_hc = (const int*)d_in[15];
    const int* dst_hc = (const int*)d_in[16];
    const int* src_bt = (const int*)d_in[17];
    const int* dst_bt = (const int*)d_in[18];
    const int* src_is = (const int*)d_in[19];
    const int* dst_is = (const int*)d_in[20];
    const int* src_pt = (const int*)d_in[21];
    const int* dst_pt = (const int*)d_in[22];
    float* out = (float*)d_out;   // output is float32 per the reference

    // ---- carve workspace (~614 MB total; R2 proved this fits) ----
    char* p = (char*)d_ws;
    auto alloc = [&](size_t bytes) -> char* {
        char* r = p;
        p += (bytes + 255) & ~(size_t)255;
        return r;
    };
    ushort_t* xt = (ushort_t*)alloc((size_t)NT * FDIM * 2);
    ushort_t* xc = (ushort_t*)alloc((size_t)NC * FDIM * 2);
    ushort_t* xf = (ushort_t*)alloc((size_t)NF * FDIM * 2);
    ushort_t* xl = (ushort_t*)alloc((size_t)NC * FDIM * 2);
    ushort_t* xr = (ushort_t*)alloc((size_t)NC * FDIM * 2);
    float* o_c = (float*)alloc((size_t)NC * FDIM * 4);
    float* o_t = (float*)alloc((size_t)NT * FDIM * 4);
    float* o_f = (float*)alloc((size_t)NF * FDIM * 4);
    float* logitb = (float*)alloc((size_t)E_HC * NHEAD * 4);
    unsigned* mbuf = (unsigned*)alloc((size_t)NC * NHEAD * 4);
    float* den = (float*)alloc((size_t)NC * NHEAD * 4);
    if ((size_t)(p - (char*)d_ws) > ws_size) return;  // ws too small -> zeros out

    auto grid_for = [&](int M, int N) { return dim3((M + BM - 1) / BM, N / BN); };
    // A=fp32, C=bf16 (input projections)
    auto gemm_fb = [&](const float* A, const float* W, const float* bias,
                       ushort_t* C, int M, int N, int K, int act) {
        hipLaunchKernelGGL((gemm_k<0, 1>), grid_for(M, N), dim3(256), 0, stream,
                           (const void*)A, W, bias, (void*)C, M, N, K, act);
    };
    // A=bf16, C=bf16 (edge projections)
    auto gemm_bb = [&](const ushort_t* A, const float* W, const float* bias,
                       ushort_t* C, int M, int N, int K, int act) {
        hipLaunchKernelGGL((gemm_k<1, 1>), grid_for(M, N), dim3(256), 0, stream,
                           (const void*)A, W, bias, (void*)C, M, N, K, act);
    };
    // A=bf16, C=fp32 (output projections -> d_out)
    auto gemm_bf = [&](const ushort_t* A, const float* W, const float* bias,
                       float* C, int M, int N, int K, int act) {
        hipLaunchKernelGGL((gemm_k<1, 0>), grid_for(M, N), dim3(256), 0, stream,
                           (const void*)A, W, bias, (void*)C, M, N, K, act);
    };

    // ---- input projections: [N,256] @ [256,64] + b, leaky 0.01 ----
    gemm_fb(x_table, lin_w + 0 * 256 * 64, lin_b + 0 * 64, xt, NT, 64, 256, 1);
    gemm_fb(x_column, lin_w + 1 * 256 * 64, lin_b + 1 * 64, xc, NC, 64, 256, 1);
    gemm_fb(x_fk, lin_w + 2 * 256 * 64, lin_b + 2 * 64, xf, NF, 64, 256, 1);

    auto run_edge_type = [&](const ushort_t* xsrc, int Ns, const ushort_t* xdst, int Nd,
                             const int* src, const int* dst, int E,
                             const float* Wl_t, const float* Wr_t,
                             const float* att_t, float* obuf, int Kd) {
        gemm_bb(xsrc, Wl_t, nullptr, xl, Ns, FDIM, Kd, 0);
        gemm_bb(xdst, Wr_t, nullptr, xr, Nd, FDIM, Kd, 0);
        int nmd = Nd * NHEAD;
        hipLaunchKernelGGL(init_md_k, dim3((nmd + 255) / 256), dim3(256), 0, stream,
                           mbuf, den, nmd);
        hipLaunchKernelGGL(edge_logits_k, dim3((E + 3) / 4), dim3(256), 0, stream,
                           xl, xr, att_t, src, dst, logitb, mbuf, E);
        hipLaunchKernelGGL(edge_z_k, dim3((E * NHEAD + 255) / 256), dim3(256), 0, stream,
                           dst, logitb, mbuf, den, E);
        hipLaunchKernelGGL(edge_scatter_k, dim3((E + 3) / 4), dim3(256), 0, stream,
                           xl, src, dst, logitb, den, obuf, E);
    };

    for (int l = 0; l < 2; l++) {
        const float* Wl = l ? Wl1 : Wl0;
        const float* Wr = l ? Wr1 : Wr0;
        const float* att = l ? att1 : att0;
        const float* bb = l ? b1 : b0;
        int Kd = l ? 256 : 64;
        size_t wstep = (size_t)Kd * FDIM;

        hipLaunchKernelGGL(fill_bias_k, dim3((NT * FDIM + 255) / 256), dim3(256), 0, stream,
                           o_t, bb + 1 * FDIM, (const float*)nullptr, NT * FDIM);
        hipLaunchKernelGGL(fill_bias_k, dim3((NF * FDIM + 255) / 256), dim3(256), 0, stream,
                           o_f, bb + 2 * FDIM, (const float*)nullptr, NF * FDIM);
        hipLaunchKernelGGL(fill_bias_k, dim3((NC * FDIM + 255) / 256), dim3(256), 0, stream,
                           o_c, bb + 0 * FDIM, bb + 3 * FDIM, NC * FDIM);

        run_edge_type(xt, NT, xc, NC, src_hc, dst_hc, E_HC,
                      Wl + 0 * wstep, Wr + 0 * wstep, att + 0 * FDIM, o_c, Kd);
        run_edge_type(xc, NC, xt, NT, src_bt, dst_bt, E_BT,
                      Wl + 1 * wstep, Wr + 1 * wstep, att + 1 * FDIM, o_t, Kd);
        run_edge_type(xc, NC, xf, NF, src_is, dst_is, E_IS,
                      Wl + 2 * wstep, Wr + 2 * wstep, att + 2 * FDIM, o_f, Kd);
        run_edge_type(xf, NF, xc, NC, src_pt, dst_pt, E_PT,
                      Wl + 3 * wstep, Wr + 3 * wstep, att + 3 * FDIM, o_c, Kd);

        hipLaunchKernelGGL(combine_elu_k, dim3((NT * FDIM + 255) / 256), dim3(256), 0, stream,
                           o_t, xt, 1.0f, NT * FDIM);
        hipLaunchKernelGGL(combine_elu_k, dim3((NC * FDIM + 255) / 256), dim3(256), 0, stream,
                           o_c, xc, 0.5f, NC * FDIM);
        hipLaunchKernelGGL(combine_elu_k, dim3((NF * FDIM + 255) / 256), dim3(256), 0, stream,
                           o_f, xf, 1.0f, NF * FDIM);
    }

    // ---- output projections -> d_out (concat xt, xc, xf), fp32 ----
    gemm_bf(xt, out_w + 0 * 256 * 256, out_b + 0 * 256, out, NT, 256, 256, 0);
    gemm_bf(xc, out_w + 1 * 256 * 256, out_b + 1 * 256, out + (size_t)NT * FDIM, NC, 256, 256, 0);
    gemm_bf(xf, out_w + 2 * 256 * 256, out_b + 2 * 256, out + (size_t)(NT + NC) * FDIM, NF, 256, 256, 0);
}